// Round 15
// baseline (257.884 us; speedup 1.0000x reference)
//
#include <hip/hip_runtime.h>
#include <hip/hip_bf16.h>
#include <math.h>

typedef unsigned short ushort_t;
typedef unsigned int uint_t;
typedef __attribute__((ext_vector_type(8))) short short8;
typedef __attribute__((ext_vector_type(4))) float floatx4;
typedef __attribute__((ext_vector_type(2))) uint_t uint2v;

#define BB 4
#define TT 2048
#define CCH 1024
#define HH 16
#define HDIM 64
#define MROWS (BB * TT) /* 8192 */

#define GLDS(g, l)                                                        \
  __builtin_amdgcn_global_load_lds(                                       \
      (const __attribute__((address_space(1))) void*)(g),                 \
      (__attribute__((address_space(3))) void*)(l), 16, 0, 0)

#if __has_builtin(__builtin_amdgcn_exp2f)
#define EXP2(x) __builtin_amdgcn_exp2f(x)
#else
#define EXP2(x) exp2f(x)
#endif

__device__ __forceinline__ ushort_t f2bf(float f) {
  union { float f; uint_t u; } x;
  x.f = f;
  uint_t u = x.u;
  u += 0x7FFFu + ((u >> 16) & 1u); // RNE
  return (ushort_t)(u >> 16);
}

__device__ __forceinline__ float bf2f(ushort_t v) {
  union { uint_t u; float f; } x;
  x.u = ((uint_t)v) << 16;
  return x.f;
}

// truncating bf16 pair pack (low = a, high = b); |err| <= 2^-8 relative
__device__ __forceinline__ uint_t pk_trunc(float a, float b) {
  union { float f; uint_t u; } xa, xb;
  xa.f = a; xb.f = b;
  return (xa.u >> 16) | (xb.u & 0xFFFF0000u);
}

__device__ __forceinline__ uint_t pk_rne(float a, float b) {
  return (uint_t)f2bf(a) | ((uint_t)f2bf(b) << 16);
}

// ---------------------------------------------------------------------------
// inline dtype detect: used by prep_all ONLY. Gemms read the flag prep_all
// writes (round-6 post-mortem: inline detect inside gemm cost ~4 us/launch).
// ---------------------------------------------------------------------------
__device__ __forceinline__ bool inline_detect(const uint_t* __restrict__ x) {
  __shared__ int dcnt;
  if (threadIdx.x == 0) dcnt = 0;
  __syncthreads();
  int c = 0;
  for (int i = threadIdx.x; i < 1024; i += 256) {
    uint_t w = x[i];
    uint_t e = (w >> 7) & 0xFFu;
    if (e >= 100u && e <= 150u) c++;
  }
  atomicAdd(&dcnt, c);
  __syncthreads();
  return dcnt > 512;
}

// ---------------------------------------------------------------------------
// prep_all: fused {detect + flag write + prep_x (8 elem/thread) + both
// weight transposes}. One launch replaces four. Block ranges:
//   [0,4096)        x -> xb copy/cast (uint4 I/O)
//   [4096,4864)     w_qkv  [1024][3072] -> wqkvT [3072][1024]
//   [4864,5120)     w_proj [1024][1024] -> wprojT [1024][1024]
// ---------------------------------------------------------------------------
__global__ __launch_bounds__(256) void prep_all(
    const void* __restrict__ x, const void* __restrict__ w_qkv,
    const void* __restrict__ w_proj, ushort_t* __restrict__ xb,
    ushort_t* __restrict__ wqkvT, ushort_t* __restrict__ wprojT,
    uint_t* __restrict__ flag) {
  __shared__ float tile[64][65];
  const bool inbf = inline_detect((const uint_t*)x);
  const int tid = threadIdx.x;
  int bid = blockIdx.x;

  if (bid == 0 && tid == 0) *flag = inbf ? 1u : 0u;

  if (bid < 4096) {  // ---- x -> xb, 8 elems/thread ----
    size_t base = ((size_t)bid * 256 + tid) * 8;
    if (inbf) {
      *(uint4*)&xb[base] = *(const uint4*)&((const ushort_t*)x)[base];
    } else {
      const float* xf = (const float*)x;
      float4 a = *(const float4*)&xf[base];
      float4 c = *(const float4*)&xf[base + 4];
      uint4 o;
      o.x = pk_rne(a.x, a.y);
      o.y = pk_rne(a.z, a.w);
      o.z = pk_rne(c.x, c.y);
      o.w = pk_rne(c.z, c.w);
      *(uint4*)&xb[base] = o;
    }
    return;
  }

  // ---- weight transpose+cast: src [1024][N] -> dst bf16 [N][1024] ----
  bid -= 4096;
  const void* w;
  ushort_t* wT;
  int N, bx, by;
  if (bid < 768) {
    w = w_qkv; wT = wqkvT; N = 3072; bx = bid % 48; by = bid / 48;
  } else {
    bid -= 768;
    w = w_proj; wT = wprojT; N = 1024; bx = bid % 16; by = bid / 16;
  }
  const int bn = bx * 64;  // dst-row / src-col tile
  const int bk = by * 64;  // src-row / dst-col tile
  if (!inbf) {
    const float* src = (const float*)w;
#pragma unroll
    for (int p = 0; p < 4; p++) {
      int r = p * 16 + (tid >> 4);
      int c = (tid & 15) * 4;
      float4 v = *(const float4*)&src[(size_t)(bk + r) * N + bn + c];
      tile[r][c] = v.x; tile[r][c + 1] = v.y;
      tile[r][c + 2] = v.z; tile[r][c + 3] = v.w;
    }
  } else {
    const ushort_t* src = (const ushort_t*)w;
#pragma unroll
    for (int p = 0; p < 4; p++) {
      int r = p * 16 + (tid >> 4);
      int c = (tid & 15) * 4;
      const ushort_t* s = &src[(size_t)(bk + r) * N + bn + c];
      tile[r][c] = bf2f(s[0]); tile[r][c + 1] = bf2f(s[1]);
      tile[r][c + 2] = bf2f(s[2]); tile[r][c + 3] = bf2f(s[3]);
    }
  }
  __syncthreads();
#pragma unroll
  for (int p = 0; p < 8; p++) {
    int nn = p * 8 + (tid >> 5);
    int kk = (tid & 31) * 2;
    uint_t u = pk_rne(tile[kk][nn], tile[kk + 1][nn]);
    *(uint_t*)&wT[(size_t)(bn + nn) * 1024 + bk + kk] = u;
  }
}

// ---------------------------------------------------------------------------
// GEMM v3+ (QKV) — UNCHANGED from round 14 (measured 75.7 us, FETCH 45 MB):
// 128x128 tile, v3 schedule (3 buffers, counted vmcnt, ONE barrier/K-step,
// reg-dbuf frags, k-slot XOR swizzle, setprio), 2-D rect XCD partition
// (A-slab 4 MB + hot B-panel 256 KB per XCD, bm-fastest), packed V-stores.
// ---------------------------------------------------------------------------
__global__ __launch_bounds__(256, 3) void gemm_qkv(
    const ushort_t* __restrict__ A, const ushort_t* __restrict__ Bt,
    const void* __restrict__ bias,
    ushort_t* __restrict__ q_out, ushort_t* __restrict__ k_out,
    ushort_t* __restrict__ v_out,
    const uint_t* __restrict__ flag) {
  alignas(16) __shared__ ushort_t As[3][128 * 32];
  alignas(16) __shared__ ushort_t Bs[3][128 * 32];

  const int tid = threadIdx.x;
  const int wave = tid >> 6, lane = tid & 63;
  const int quad = lane >> 4, l16 = lane & 15;
  const int wm = (wave & 1) * 64, wn = (wave >> 1) * 64;

  // 2-D rect XCD partition (bijective, 1536 = 8 rects x 192):
  const int flat = blockIdx.x;
  const int xcd = flat & 7, idx = flat >> 3;     // idx in [0,192)
  const int bm_t = (xcd & 3) * 16 + (idx & 15);  // bm tile in [0,64)
  const int bn_t = (xcd >> 2) * 12 + (idx >> 4); // bn tile in [0,24)
  const int bm = bm_t * 128;
  const int bn = bn_t * 128;

  const int r0 = tid >> 2;
  const int co = ((tid & 3) ^ ((tid >> 3) & 3)) * 8;
  const int xs = (quad ^ ((l16 >> 1) & 3)) * 8;

  floatx4 acc[4][4] = {};
  short8 afA[4], bfA[4], afB[4], bfB[4];

#define STAGE_G(kt, bf_)                                                     \
  do {                                                                       \
    const int k0_ = (kt) * 32;                                               \
    GLDS(&A[(size_t)(bm + r0) * 1024 + k0_ + co], &As[bf_][tid * 8]);        \
    GLDS(&A[(size_t)(bm + r0 + 64) * 1024 + k0_ + co],                       \
         &As[bf_][(tid + 256) * 8]);                                         \
    GLDS(&Bt[(size_t)(bn + r0) * 1024 + k0_ + co], &Bs[bf_][tid * 8]);       \
    GLDS(&Bt[(size_t)(bn + r0 + 64) * 1024 + k0_ + co],                      \
         &Bs[bf_][(tid + 256) * 8]);                                         \
  } while (0)

  STAGE_G(0, 0);
  STAGE_G(1, 1);
  STAGE_G(2, 2);
  asm volatile("s_waitcnt vmcnt(8)" ::: "memory");  // tile 0 landed
  __builtin_amdgcn_s_barrier();
  __builtin_amdgcn_sched_barrier(0);
#pragma unroll
  for (int i = 0; i < 4; i++)
    afA[i] = *(const short8*)&As[0][(wm + i * 16 + l16) * 32 + xs];
#pragma unroll
  for (int i = 0; i < 4; i++)
    bfA[i] = *(const short8*)&Bs[0][(wn + i * 16 + l16) * 32 + xs];
  asm volatile("s_waitcnt lgkmcnt(0)" ::: "memory");
  __builtin_amdgcn_sched_barrier(0);

#define KBODY(kt, CA, CB, NA, NB)                                            \
  {                                                                          \
    if ((kt) <= 29)                                                          \
      asm volatile("s_waitcnt vmcnt(4)" ::: "memory");                       \
    else if ((kt) == 30)                                                     \
      asm volatile("s_waitcnt vmcnt(0)" ::: "memory");                       \
    __builtin_amdgcn_s_barrier();                                            \
    __builtin_amdgcn_sched_barrier(0);                                       \
    const int cs_ = (kt) % 3, ns_ = ((kt) + 1) % 3;                          \
    if ((kt) + 3 < 32) STAGE_G((kt) + 3, cs_);                               \
    if ((kt) + 1 < 32) {                                                     \
      _Pragma("unroll") for (int i = 0; i < 4; i++)                          \
          NA[i] = *(const short8*)&As[ns_][(wm + i * 16 + l16) * 32 + xs];   \
      _Pragma("unroll") for (int i = 0; i < 4; i++)                          \
          NB[i] = *(const short8*)&Bs[ns_][(wn + i * 16 + l16) * 32 + xs];   \
    }                                                                        \
    __builtin_amdgcn_s_setprio(1);                                           \
    _Pragma("unroll") for (int mi = 0; mi < 4; mi++)                         \
        _Pragma("unroll") for (int ni = 0; ni < 4; ni++)                     \
            acc[mi][ni] = __builtin_amdgcn_mfma_f32_16x16x32_bf16(           \
                CA[mi], CB[ni], acc[mi][ni], 0, 0, 0);                       \
    __builtin_amdgcn_s_setprio(0);                                           \
    asm volatile("s_waitcnt lgkmcnt(0)" ::: "memory");                       \
    __builtin_amdgcn_sched_barrier(0);                                       \
  }

  for (int kt = 0; kt < 32; kt += 2) {
    KBODY(kt, afA, bfA, afB, bfB);
    KBODY(kt + 1, afB, bfB, afA, bfA);
  }
#undef KBODY
#undef STAGE_G

  const bool inbf = (*flag != 0);

#pragma unroll
  for (int mi = 0; mi < 4; mi++) {
#pragma unroll
    for (int ni = 0; ni < 4; ni++) {
      const int row0 = bm + wm + mi * 16 + quad * 4;  // 4-aligned
      const int col = bn + wn + ni * 16 + l16;
      float bsv = inbf ? bf2f(((const ushort_t*)bias)[col])
                       : ((const float*)bias)[col];
      float v0 = acc[mi][ni][0] + bsv, v1 = acc[mi][ni][1] + bsv;
      float v2 = acc[mi][ni][2] + bsv, v3 = acc[mi][ni][3] + bsv;
      const int b = row0 >> 11, t0 = row0 & 2047;  // quad of rows same b
      const int which = col >> 10, rem = col & 1023;  // uniform per (ni)
      const int h = rem >> 6, d = rem & 63;
      const size_t bh = (size_t)(b * HH + h);
      if (which == 2) {
        // V transposed [B,H,64,T]: 4 consecutive t, same d -> one 8B store
        uint2v u;
        u[0] = pk_rne(v0, v1);
        u[1] = pk_rne(v2, v3);
        *(uint2v*)&v_out[(bh * HDIM + d) * TT + t0] = u;
      } else {
        ushort_t* o = (which == 0) ? q_out : k_out;
        o[(bh * TT + t0 + 0) * HDIM + d] = f2bf(v0);
        o[(bh * TT + t0 + 1) * HDIM + d] = f2bf(v1);
        o[(bh * TT + t0 + 2) * HDIM + d] = f2bf(v2);
        o[(bh * TT + t0 + 3) * HDIM + d] = f2bf(v3);
      }
    }
  }
}

// ---------------------------------------------------------------------------
// GEMM proj v2 (round-15): exact mirror of the QKV-winning configuration.
// Budget analysis: proj ~= 75 us (just under the 75.56 top-5 cutoff) at
// ~245 TF — the worst per-FLOP kernel. Two suspects in the r14 proj:
// (a) 64x128 tiles = 8-MFMA slots (half QKV's MFMA density at the same
// fixed slot cost); (b) the rect gave each XCD A 2MB + FULL B 2MB = 4MB =
// exactly L2 -> thrash-prone. v2: 128x128 tile + the v3 4-wave schedule
// (K-loop byte-identical to gemm_qkv) + QKV-mirror rect: 512 = 8 x 64,
// XCD x owns bm in [16*(x&3),+16) x bn in [4*(x>>2),+4), bm-fastest ->
// A-slab 4 MB + hot B-panel 256 KB (the measured-good cache geometry).
// 512 blocks -> 2/CU single round.
// ---------------------------------------------------------------------------
__global__ __launch_bounds__(256, 3) void gemm_proj(
    const ushort_t* __restrict__ A, const ushort_t* __restrict__ Bt,
    const void* __restrict__ bias, void* __restrict__ outp,
    const uint_t* __restrict__ flag) {
  alignas(16) __shared__ ushort_t As[3][128 * 32];
  alignas(16) __shared__ ushort_t Bs[3][128 * 32];

  const int tid = threadIdx.x;
  const int wave = tid >> 6, lane = tid & 63;
  const int quad = lane >> 4, l16 = lane & 15;
  const int wm = (wave & 1) * 64, wn = (wave >> 1) * 64;

  // QKV-mirror rect (bijective, 512 = 8 rects x 64):
  const int flat = blockIdx.x;
  const int xcd = flat & 7, idx = flat >> 3;     // idx in [0,64)
  const int bm_t = (xcd & 3) * 16 + (idx & 15);  // bm tile in [0,64)
  const int bn_t = (xcd >> 2) * 4 + (idx >> 4);  // bn tile in [0,8)
  const int bm = bm_t * 128;
  const int bn = bn_t * 128;

  const int r0 = tid >> 2;
  const int co = ((tid & 3) ^ ((tid >> 3) & 3)) * 8;
  const int xs = (quad ^ ((l16 >> 1) & 3)) * 8;

  floatx4 acc[4][4] = {};
  short8 afA[4], bfA[4], afB[4], bfB[4];

#define STAGE_G(kt, bf_)                                                     \
  do {                                                                       \
    const int k0_ = (kt) * 32;                                               \
    GLDS(&A[(size_t)(bm + r0) * 1024 + k0_ + co], &As[bf_][tid * 8]);        \
    GLDS(&A[(size_t)(bm + r0 + 64) * 1024 + k0_ + co],                       \
         &As[bf_][(tid + 256) * 8]);                                         \
    GLDS(&Bt[(size_t)(bn + r0) * 1024 + k0_ + co], &Bs[bf_][tid * 8]);       \
    GLDS(&Bt[(size_t)(bn + r0 + 64) * 1024 + k0_ + co],                      \
         &Bs[bf_][(tid + 256) * 8]);                                         \
  } while (0)

  STAGE_G(0, 0);
  STAGE_G(1, 1);
  STAGE_G(2, 2);
  asm volatile("s_waitcnt vmcnt(8)" ::: "memory");  // tile 0 landed
  __builtin_amdgcn_s_barrier();
  __builtin_amdgcn_sched_barrier(0);
#pragma unroll
  for (int i = 0; i < 4; i++)
    afA[i] = *(const short8*)&As[0][(wm + i * 16 + l16) * 32 + xs];
#pragma unroll
  for (int i = 0; i < 4; i++)
    bfA[i] = *(const short8*)&Bs[0][(wn + i * 16 + l16) * 32 + xs];
  asm volatile("s_waitcnt lgkmcnt(0)" ::: "memory");
  __builtin_amdgcn_sched_barrier(0);

#define KBODY(kt, CA, CB, NA, NB)                                            \
  {                                                                          \
    if ((kt) <= 29)                                                          \
      asm volatile("s_waitcnt vmcnt(4)" ::: "memory");                       \
    else if ((kt) == 30)                                                     \
      asm volatile("s_waitcnt vmcnt(0)" ::: "memory");                       \
    __builtin_amdgcn_s_barrier();                                            \
    __builtin_amdgcn_sched_barrier(0);                                       \
    const int cs_ = (kt) % 3, ns_ = ((kt) + 1) % 3;                          \
    if ((kt) + 3 < 32) STAGE_G((kt) + 3, cs_);                               \
    if ((kt) + 1 < 32) {                                                     \
      _Pragma("unroll") for (int i = 0; i < 4; i++)                          \
          NA[i] = *(const short8*)&As[ns_][(wm + i * 16 + l16) * 32 + xs];   \
      _Pragma("unroll") for (int i = 0; i < 4; i++)                          \
          NB[i] = *(const short8*)&Bs[ns_][(wn + i * 16 + l16) * 32 + xs];   \
    }                                                                        \
    __builtin_amdgcn_s_setprio(1);                                           \
    _Pragma("unroll") for (int mi = 0; mi < 4; mi++)                         \
        _Pragma("unroll") for (int ni = 0; ni < 4; ni++)                     \
            acc[mi][ni] = __builtin_amdgcn_mfma_f32_16x16x32_bf16(           \
                CA[mi], CB[ni], acc[mi][ni], 0, 0, 0);                       \
    __builtin_amdgcn_s_setprio(0);                                           \
    asm volatile("s_waitcnt lgkmcnt(0)" ::: "memory");                       \
    __builtin_amdgcn_sched_barrier(0);                                       \
  }

  for (int kt = 0; kt < 32; kt += 2) {
    KBODY(kt, afA, bfA, afB, bfB);
    KBODY(kt + 1, afB, bfB, afA, bfA);
  }
#undef KBODY
#undef STAGE_G

  const bool inbf = (*flag != 0);

#pragma unroll
  for (int mi = 0; mi < 4; mi++) {
#pragma unroll
    for (int ni = 0; ni < 4; ni++) {
#pragma unroll
      for (int r = 0; r < 4; r++) {
        int row = bm + wm + mi * 16 + quad * 4 + r;
        int col = bn + wn + ni * 16 + l16;
        float bsv = inbf ? bf2f(((const ushort_t*)bias)[col])
                         : ((const float*)bias)[col];
        float v = acc[mi][ni][r] + bsv;
        size_t idx2 = (size_t)row * CCH + col;
        if (inbf)
          ((ushort_t*)outp)[idx2] = f2bf(v);
        else
          ((float*)outp)[idx2] = v;
      }
    }
  }
}

// ---------------------------------------------------------------------------
// Flash attention v6: occupancy-split (stable since round 1; ~62 us).
//   One block per (bh, qt) -> 1024 blocks; each of the 4 waves owns one
//   32-row strip. Depth-1 prefetch, single barrier per tile. Softmax
//   denominator via MFMA row-sum. Long blocks dispatch first.
// Q,K: [B,H,T,64]. Vt: [B,H,64,T]. Out attb: [B,T,H*64] bf16.
// ---------------------------------------------------------------------------
__global__ __launch_bounds__(256, 3) void flash_attn(
    const ushort_t* __restrict__ qb, const ushort_t* __restrict__ kb,
    const ushort_t* __restrict__ vtb, ushort_t* __restrict__ attb) {
  alignas(16) __shared__ ushort_t Ks[2][64 * 64];
  alignas(16) __shared__ ushort_t Vs[2][64 * 64];
  alignas(16) __shared__ ushort_t Ps[4][32 * 72];

  const int tid = threadIdx.x;
  const int wave = tid >> 6, lane = tid & 63;
  const int quad = lane >> 4, l16 = lane & 15;
  const int bh = blockIdx.x;          // XCD-swizzle: bh fastest-varying
  const int b = bh >> 4, h = bh & 15;
  const int qt = 15 - blockIdx.y;     // long blocks dispatch first
  const int qbs = qt * 128 + wave * 32;

  const ushort_t* Q = qb + (size_t)bh * TT * HDIM;
  const ushort_t* K = kb + (size_t)bh * TT * HDIM;
  const ushort_t* Vt = vtb + (size_t)bh * HDIM * TT;
  ushort_t* Pw = Ps[wave];

  const float SC = 0.015625f * 1.44269504089f; // (1/64)*log2(e)

  // Q fragments, pre-scaled by SC
  short8 qf[2][2];
#pragma unroll
  for (int m = 0; m < 2; m++)
#pragma unroll
    for (int ks = 0; ks < 2; ks++) {
      short8 a = *(const short8*)&Q[(size_t)(qbs + m * 16 + l16) * HDIM +
                                    ks * 32 + quad * 8];
#pragma unroll
      for (int j = 0; j < 8; j++)
        a[j] = (short)f2bf(bf2f((ushort_t)a[j]) * SC);
      qf[m][ks] = a;
    }

  // A-fragment of all-ones (bf16 1.0) for the row-sum MFMA
  short8 ones;
#pragma unroll
  for (int j = 0; j < 8; j++) ones[j] = (short)0x3F80;

  floatx4 o[2][4] = {};
  floatx4 osum[2] = {};

  const int lt = (qbs + 31) >> 6;  // this wave's last live tile
  const int ntiles = 2 * qt + 2;   // block-uniform trip count
  int cur = 0;

  // prologue: stage tile 0 into buffer 0 (first barrier drains vmcnt)
#pragma unroll
  for (int s2 = 0; s2 < 2; s2++) {
    int c = tid + s2 * 256;
    int row = c >> 3, gc = ((c & 7) ^ (row & 7)) * 8;
    GLDS(&K[(size_t)row * HDIM + gc], &Ks[0][c * 8]);
    GLDS(&Vt[(size_t)row * TT + gc], &Vs[0][c * 8]);
  }

  for (int kt = 0; kt < ntiles; kt++) {
    const int kt0 = kt * 64;
    cur = kt & 1;
    // Single barrier per tile: implicit vmcnt(0) drain completes tile kt's
    // GLDS (issued last iteration under compute), and proves all waves are
    // done reading buf[cur^1] before it is restaged.
    __syncthreads();

    if (kt + 1 < ntiles) {
      const int n0 = kt0 + 64;
#pragma unroll
      for (int s2 = 0; s2 < 2; s2++) {
        int c = tid + s2 * 256;
        int row = c >> 3, gc = ((c & 7) ^ (row & 7)) * 8;
        GLDS(&K[(size_t)(n0 + row) * HDIM + gc], &Ks[cur ^ 1][c * 8]);
        GLDS(&Vt[(size_t)row * TT + n0 + gc], &Vs[cur ^ 1][c * 8]);
      }
    }

    if (kt > lt) continue;  // wave-uniform: this strip is done (barrier-safe)

    short8 kf[4][2];
#pragma unroll
    for (int sub = 0; sub < 4; sub++)
#pragma unroll
      for (int ks = 0; ks < 2; ks++) {
        int col = (ks * 32 + quad * 8) ^ ((l16 & 7) * 8);
        kf[sub][ks] = *(const short8*)&Ks[cur][(sub * 16 + l16) * 64 + col];
      }

#pragma unroll
    for (int m = 0; m < 2; m++) {
      floatx4 s[4] = {};
      __builtin_amdgcn_s_setprio(1);
#pragma unroll
      for (int sub = 0; sub < 4; sub++)
#pragma unroll
        for (int ks = 0; ks < 2; ks++)
          s[sub] = __builtin_amdgcn_mfma_f32_16x16x32_bf16(
              kf[sub][ks], qf[m][ks], s[sub], 0, 0, 0); // S^T tile
      __builtin_amdgcn_s_setprio(0);

      const bool full = (kt0 + 63 <= qbs + m * 16); // wave-uniform
      const int qrow = qbs + m * 16 + l16;
#pragma unroll
      for (int sub = 0; sub < 4; sub++) {
#pragma unroll
        for (int r = 0; r < 4; r++) {
          float p = EXP2(s[sub][r]);
          if (!full) {
            int key = kt0 + sub * 16 + quad * 4 + r;
            p = (key <= qrow) ? p : 0.0f;
          }
          s[sub][r] = p;
        }
        // P[q=l16][key-local sub*16+quad*4+{0..3}]: 4 contiguous bf16
        uint2v u;
        u[0] = pk_trunc(s[sub][0], s[sub][1]);
        u[1] = pk_trunc(s[sub][2], s[sub][3]);
        *(uint2v*)&Pw[(m * 16 + l16) * 72 + sub * 16 + quad * 4] = u;
      }
    }

    short8 pf[2][2];
#pragma unroll
    for (int m = 0; m < 2; m++)
#pragma unroll
      for (int ks = 0; ks < 2; ks++)
        pf[m][ks] =
            *(const short8*)&Pw[(m * 16 + l16) * 72 + ks * 32 + quad * 8];

    __builtin_amdgcn_s_setprio(1);
#pragma unroll
    for (int m = 0; m < 2; m++)
#pragma unroll
      for (int ks = 0; ks < 2; ks++)
        osum[m] = __builtin_amdgcn_mfma_f32_16x16x32_bf16(
            ones, pf[m][ks], osum[m], 0, 0, 0); // row-sum: C[r][q]=sum_k P

#pragma unroll
    for (int n = 0; n < 4; n++) {
#pragma unroll
      for (int ks = 0; ks < 2; ks++) {
        int col = (ks * 32 + quad * 8) ^ ((l16 & 7) * 8);
        short8 vf = *(const short8*)&Vs[cur][(n * 16 + l16) * 64 + col];
#pragma unroll
        for (int m = 0; m < 2; m++)
          o[m][n] = __builtin_amdgcn_mfma_f32_16x16x32_bf16(
              vf, pf[m][ks], o[m][n], 0, 0, 0); // O^T tile
      }
    }
    __builtin_amdgcn_s_setprio(0);
  }

  // epilogue: osum[m] already holds the complete row-sum for q=l16
#pragma unroll
  for (int m = 0; m < 2; m++) {
    float inv = 1.0f / osum[m][0];
    ushort_t* base =
        &attb[((size_t)(b * TT + qbs + m * 16 + l16)) * CCH + h * HDIM];
#pragma unroll
    for (int n = 0; n < 4; n++) {
      uint2v u;
      u[0] = pk_rne(o[m][n][0] * inv, o[m][n][1] * inv);
      u[1] = pk_rne(o[m][n][2] * inv, o[m][n][3] * inv);
      *(uint2v*)&base[n * 16 + quad * 4] = u;
    }
  }
}

// ---------------------------------------------------------------------------
// Workspace (bf16 elements), ~59 MB:
//   xb/attb [8192,1024] @ 0          (8,388,608)  attb overlays xb (dead)
//   wqkvT  [3072,1024]  @ 8,388,608  (3,145,728)
//   wprojT [1024,1024]  @ 11,534,336 (1,048,576)
//   qb     [B,H,T,64]   @ 12,582,912 (8,388,608)
//   kb     [B,H,T,64]   @ 20,971,520 (8,388,608)
//   flag   (uint)       @ 29,360,128
// vtb [B,H,64,T] lives in d_out (dead before proj GEMM writes it).
// Launch graph: prep_all -> gemm_qkv -> flash_attn -> gemm_proj (4 kernels).
// ---------------------------------------------------------------------------
extern "C" void kernel_launch(void* const* d_in, const int* in_sizes, int n_in,
                              void* d_out, int out_size, void* d_ws, size_t ws_size,
                              hipStream_t stream) {
  const void* x      = d_in[0];
  const void* w_qkv  = d_in[1];
  const void* b_qkv  = d_in[2];
  const void* w_proj = d_in[3];
  const void* b_proj = d_in[4];

  ushort_t* ws = (ushort_t*)d_ws;
  ushort_t* xb     = ws;
  ushort_t* wqkvT  = ws + 8388608;
  ushort_t* wprojT = ws + 11534336;
  ushort_t* qb     = ws + 12582912;
  ushort_t* kb     = ws + 20971520;
  ushort_t* attb   = xb;
  uint_t*   flag   = (uint_t*)(ws + 29360128);
  ushort_t* vtb    = (ushort_t*)d_out;

  prep_all<<<dim3(4096 + 768 + 256), dim3(256), 0, stream>>>(
      x, w_qkv, w_proj, xb, wqkvT, wprojT, flag);

  // 1D grid, 2-D rect XCD partition (1536 = 8 x 192)
  gemm_qkv<<<dim3((MROWS / 128) * ((3 * CCH) / 128)), dim3(256), 0, stream>>>(
      xb, wqkvT, b_qkv, qb, kb, vtb, flag);

  // grid (bh, qt): bh%8 -> XCD (L2 K/V reuse); y=0 (qt=15, longest) first
  flash_attn<<<dim3(BB * HH, 16), dim3(256), 0, stream>>>(qb, kb, vtb, attb);

  // 1D grid, QKV-mirror rect partition (512 = 8 x 64); 128x128 tile
  gemm_proj<<<dim3((MROWS / 128) * (CCH / 128)), dim3(256), 0, stream>>>(
      attb, wprojT, b_proj, d_out, flag);
}

// Round 16
// 252.801 us; speedup vs baseline: 1.0201x; 1.0201x over previous
//
#include <hip/hip_runtime.h>
#include <hip/hip_bf16.h>
#include <math.h>

typedef unsigned short ushort_t;
typedef unsigned int uint_t;
typedef __attribute__((ext_vector_type(8))) short short8;
typedef __attribute__((ext_vector_type(4))) float floatx4;
typedef __attribute__((ext_vector_type(2))) uint_t uint2v;

#define BB 4
#define TT 2048
#define CCH 1024
#define HH 16
#define HDIM 64
#define MROWS (BB * TT) /* 8192 */

#define GLDS(g, l)                                                        \
  __builtin_amdgcn_global_load_lds(                                       \
      (const __attribute__((address_space(1))) void*)(g),                 \
      (__attribute__((address_space(3))) void*)(l), 16, 0, 0)

#if __has_builtin(__builtin_amdgcn_exp2f)
#define EXP2(x) __builtin_amdgcn_exp2f(x)
#else
#define EXP2(x) exp2f(x)
#endif

__device__ __forceinline__ ushort_t f2bf(float f) {
  union { float f; uint_t u; } x;
  x.f = f;
  uint_t u = x.u;
  u += 0x7FFFu + ((u >> 16) & 1u); // RNE
  return (ushort_t)(u >> 16);
}

__device__ __forceinline__ float bf2f(ushort_t v) {
  union { uint_t u; float f; } x;
  x.u = ((uint_t)v) << 16;
  return x.f;
}

// truncating bf16 pair pack (low = a, high = b); |err| <= 2^-8 relative
__device__ __forceinline__ uint_t pk_trunc(float a, float b) {
  union { float f; uint_t u; } xa, xb;
  xa.f = a; xb.f = b;
  return (xa.u >> 16) | (xb.u & 0xFFFF0000u);
}

__device__ __forceinline__ uint_t pk_rne(float a, float b) {
  return (uint_t)f2bf(a) | ((uint_t)f2bf(b) << 16);
}

// ---------------------------------------------------------------------------
// inline dtype detect: used by prep_all ONLY. Gemms read the flag prep_all
// writes (round-6 post-mortem: inline detect inside gemm cost ~4 us/launch).
// ---------------------------------------------------------------------------
__device__ __forceinline__ bool inline_detect(const uint_t* __restrict__ x) {
  __shared__ int dcnt;
  if (threadIdx.x == 0) dcnt = 0;
  __syncthreads();
  int c = 0;
  for (int i = threadIdx.x; i < 1024; i += 256) {
    uint_t w = x[i];
    uint_t e = (w >> 7) & 0xFFu;
    if (e >= 100u && e <= 150u) c++;
  }
  atomicAdd(&dcnt, c);
  __syncthreads();
  return dcnt > 512;
}

// ---------------------------------------------------------------------------
// prep_all: fused {detect + flag write + prep_x (8 elem/thread) + both
// weight transposes}. One launch replaces four. Block ranges:
//   [0,4096)        x -> xb copy/cast (uint4 I/O)
//   [4096,4864)     w_qkv  [1024][3072] -> wqkvT [3072][1024]
//   [4864,5120)     w_proj [1024][1024] -> wprojT [1024][1024]
// ---------------------------------------------------------------------------
__global__ __launch_bounds__(256) void prep_all(
    const void* __restrict__ x, const void* __restrict__ w_qkv,
    const void* __restrict__ w_proj, ushort_t* __restrict__ xb,
    ushort_t* __restrict__ wqkvT, ushort_t* __restrict__ wprojT,
    uint_t* __restrict__ flag) {
  __shared__ float tile[64][65];
  const bool inbf = inline_detect((const uint_t*)x);
  const int tid = threadIdx.x;
  int bid = blockIdx.x;

  if (bid == 0 && tid == 0) *flag = inbf ? 1u : 0u;

  if (bid < 4096) {  // ---- x -> xb, 8 elems/thread ----
    size_t base = ((size_t)bid * 256 + tid) * 8;
    if (inbf) {
      *(uint4*)&xb[base] = *(const uint4*)&((const ushort_t*)x)[base];
    } else {
      const float* xf = (const float*)x;
      float4 a = *(const float4*)&xf[base];
      float4 c = *(const float4*)&xf[base + 4];
      uint4 o;
      o.x = pk_rne(a.x, a.y);
      o.y = pk_rne(a.z, a.w);
      o.z = pk_rne(c.x, c.y);
      o.w = pk_rne(c.z, c.w);
      *(uint4*)&xb[base] = o;
    }
    return;
  }

  // ---- weight transpose+cast: src [1024][N] -> dst bf16 [N][1024] ----
  bid -= 4096;
  const void* w;
  ushort_t* wT;
  int N, bx, by;
  if (bid < 768) {
    w = w_qkv; wT = wqkvT; N = 3072; bx = bid % 48; by = bid / 48;
  } else {
    bid -= 768;
    w = w_proj; wT = wprojT; N = 1024; bx = bid % 16; by = bid / 16;
  }
  const int bn = bx * 64;  // dst-row / src-col tile
  const int bk = by * 64;  // src-row / dst-col tile
  if (!inbf) {
    const float* src = (const float*)w;
#pragma unroll
    for (int p = 0; p < 4; p++) {
      int r = p * 16 + (tid >> 4);
      int c = (tid & 15) * 4;
      float4 v = *(const float4*)&src[(size_t)(bk + r) * N + bn + c];
      tile[r][c] = v.x; tile[r][c + 1] = v.y;
      tile[r][c + 2] = v.z; tile[r][c + 3] = v.w;
    }
  } else {
    const ushort_t* src = (const ushort_t*)w;
#pragma unroll
    for (int p = 0; p < 4; p++) {
      int r = p * 16 + (tid >> 4);
      int c = (tid & 15) * 4;
      const ushort_t* s = &src[(size_t)(bk + r) * N + bn + c];
      tile[r][c] = bf2f(s[0]); tile[r][c + 1] = bf2f(s[1]);
      tile[r][c + 2] = bf2f(s[2]); tile[r][c + 3] = bf2f(s[3]);
    }
  }
  __syncthreads();
#pragma unroll
  for (int p = 0; p < 8; p++) {
    int nn = p * 8 + (tid >> 5);
    int kk = (tid & 31) * 2;
    uint_t u = pk_rne(tile[kk][nn], tile[kk + 1][nn]);
    *(uint_t*)&wT[(size_t)(bn + nn) * 1024 + bk + kk] = u;
  }
}

// ---------------------------------------------------------------------------
// GEMM v3+ (QKV) — UNCHANGED (r14/r15 measured 75.1-75.7 us, FETCH 45 MB):
// 128x128 tile, v3 schedule (3 buffers, counted vmcnt, ONE barrier/K-step,
// reg-dbuf frags, k-slot XOR swizzle, setprio), 2-D rect XCD partition
// (A-slab 4 MB + hot B-panel 256 KB per XCD, bm-fastest), packed V-stores.
// ---------------------------------------------------------------------------
__global__ __launch_bounds__(256, 3) void gemm_qkv(
    const ushort_t* __restrict__ A, const ushort_t* __restrict__ Bt,
    const void* __restrict__ bias,
    ushort_t* __restrict__ q_out, ushort_t* __restrict__ k_out,
    ushort_t* __restrict__ v_out,
    const uint_t* __restrict__ flag) {
  alignas(16) __shared__ ushort_t As[3][128 * 32];
  alignas(16) __shared__ ushort_t Bs[3][128 * 32];

  const int tid = threadIdx.x;
  const int wave = tid >> 6, lane = tid & 63;
  const int quad = lane >> 4, l16 = lane & 15;
  const int wm = (wave & 1) * 64, wn = (wave >> 1) * 64;

  // 2-D rect XCD partition (bijective, 1536 = 8 rects x 192):
  const int flat = blockIdx.x;
  const int xcd = flat & 7, idx = flat >> 3;     // idx in [0,192)
  const int bm_t = (xcd & 3) * 16 + (idx & 15);  // bm tile in [0,64)
  const int bn_t = (xcd >> 2) * 12 + (idx >> 4); // bn tile in [0,24)
  const int bm = bm_t * 128;
  const int bn = bn_t * 128;

  const int r0 = tid >> 2;
  const int co = ((tid & 3) ^ ((tid >> 3) & 3)) * 8;
  const int xs = (quad ^ ((l16 >> 1) & 3)) * 8;

  floatx4 acc[4][4] = {};
  short8 afA[4], bfA[4], afB[4], bfB[4];

#define STAGE_G(kt, bf_)                                                     \
  do {                                                                       \
    const int k0_ = (kt) * 32;                                               \
    GLDS(&A[(size_t)(bm + r0) * 1024 + k0_ + co], &As[bf_][tid * 8]);        \
    GLDS(&A[(size_t)(bm + r0 + 64) * 1024 + k0_ + co],                       \
         &As[bf_][(tid + 256) * 8]);                                         \
    GLDS(&Bt[(size_t)(bn + r0) * 1024 + k0_ + co], &Bs[bf_][tid * 8]);       \
    GLDS(&Bt[(size_t)(bn + r0 + 64) * 1024 + k0_ + co],                      \
         &Bs[bf_][(tid + 256) * 8]);                                         \
  } while (0)

  STAGE_G(0, 0);
  STAGE_G(1, 1);
  STAGE_G(2, 2);
  asm volatile("s_waitcnt vmcnt(8)" ::: "memory");  // tile 0 landed
  __builtin_amdgcn_s_barrier();
  __builtin_amdgcn_sched_barrier(0);
#pragma unroll
  for (int i = 0; i < 4; i++)
    afA[i] = *(const short8*)&As[0][(wm + i * 16 + l16) * 32 + xs];
#pragma unroll
  for (int i = 0; i < 4; i++)
    bfA[i] = *(const short8*)&Bs[0][(wn + i * 16 + l16) * 32 + xs];
  asm volatile("s_waitcnt lgkmcnt(0)" ::: "memory");
  __builtin_amdgcn_sched_barrier(0);

#define KBODY(kt, CA, CB, NA, NB)                                            \
  {                                                                          \
    if ((kt) <= 29)                                                          \
      asm volatile("s_waitcnt vmcnt(4)" ::: "memory");                       \
    else if ((kt) == 30)                                                     \
      asm volatile("s_waitcnt vmcnt(0)" ::: "memory");                       \
    __builtin_amdgcn_s_barrier();                                            \
    __builtin_amdgcn_sched_barrier(0);                                       \
    const int cs_ = (kt) % 3, ns_ = ((kt) + 1) % 3;                          \
    if ((kt) + 3 < 32) STAGE_G((kt) + 3, cs_);                               \
    if ((kt) + 1 < 32) {                                                     \
      _Pragma("unroll") for (int i = 0; i < 4; i++)                          \
          NA[i] = *(const short8*)&As[ns_][(wm + i * 16 + l16) * 32 + xs];   \
      _Pragma("unroll") for (int i = 0; i < 4; i++)                          \
          NB[i] = *(const short8*)&Bs[ns_][(wn + i * 16 + l16) * 32 + xs];   \
    }                                                                        \
    __builtin_amdgcn_s_setprio(1);                                           \
    _Pragma("unroll") for (int mi = 0; mi < 4; mi++)                         \
        _Pragma("unroll") for (int ni = 0; ni < 4; ni++)                     \
            acc[mi][ni] = __builtin_amdgcn_mfma_f32_16x16x32_bf16(           \
                CA[mi], CB[ni], acc[mi][ni], 0, 0, 0);                       \
    __builtin_amdgcn_s_setprio(0);                                           \
    asm volatile("s_waitcnt lgkmcnt(0)" ::: "memory");                       \
    __builtin_amdgcn_sched_barrier(0);                                       \
  }

  for (int kt = 0; kt < 32; kt += 2) {
    KBODY(kt, afA, bfA, afB, bfB);
    KBODY(kt + 1, afB, bfB, afA, bfA);
  }
#undef KBODY
#undef STAGE_G

  const bool inbf = (*flag != 0);

#pragma unroll
  for (int mi = 0; mi < 4; mi++) {
#pragma unroll
    for (int ni = 0; ni < 4; ni++) {
      const int row0 = bm + wm + mi * 16 + quad * 4;  // 4-aligned
      const int col = bn + wn + ni * 16 + l16;
      float bsv = inbf ? bf2f(((const ushort_t*)bias)[col])
                       : ((const float*)bias)[col];
      float v0 = acc[mi][ni][0] + bsv, v1 = acc[mi][ni][1] + bsv;
      float v2 = acc[mi][ni][2] + bsv, v3 = acc[mi][ni][3] + bsv;
      const int b = row0 >> 11, t0 = row0 & 2047;  // quad of rows same b
      const int which = col >> 10, rem = col & 1023;  // uniform per (ni)
      const int h = rem >> 6, d = rem & 63;
      const size_t bh = (size_t)(b * HH + h);
      if (which == 2) {
        // V transposed [B,H,64,T]: 4 consecutive t, same d -> one 8B store
        uint2v u;
        u[0] = pk_rne(v0, v1);
        u[1] = pk_rne(v2, v3);
        *(uint2v*)&v_out[(bh * HDIM + d) * TT + t0] = u;
      } else {
        ushort_t* o = (which == 0) ? q_out : k_out;
        o[(bh * TT + t0 + 0) * HDIM + d] = f2bf(v0);
        o[(bh * TT + t0 + 1) * HDIM + d] = f2bf(v1);
        o[(bh * TT + t0 + 2) * HDIM + d] = f2bf(v2);
        o[(bh * TT + t0 + 3) * HDIM + d] = f2bf(v3);
      }
    }
  }
}

// ---------------------------------------------------------------------------
// GEMM proj — REVERTED to the round-14 configuration (best total: 252.9 us).
// r15's 128-sq mirror regressed ~5 us: 512 blocks = 2 blocks/CU in a single
// round (8 waves/CU under-hides K-step latency; no second round to overlap
// tails). r14 config: 64x128 tile, 1024 blocks, 4 blocks/CU (16 waves),
// v3 schedule at 3 GLDS/thread/tile (vmcnt 6/3/0), 2-D rect XCD partition:
// XCD owns bm-tiles [16*XCD,+16) x ALL 8 bn (bn fastest) -> A-slab 2 MB +
// full B 2 MB per XCD L2. Bijective (1024 = 8 x 128).
// ---------------------------------------------------------------------------
__global__ __launch_bounds__(256, 4) void gemm_proj(
    const ushort_t* __restrict__ A, const ushort_t* __restrict__ Bt,
    const void* __restrict__ bias, void* __restrict__ outp,
    const uint_t* __restrict__ flag) {
  alignas(16) __shared__ ushort_t As[3][64 * 32];
  alignas(16) __shared__ ushort_t Bs[3][128 * 32];

  const int tid = threadIdx.x;
  const int wave = tid >> 6, lane = tid & 63;
  const int quad = lane >> 4, l16 = lane & 15;
  const int wm = (wave & 1) * 32, wn = (wave >> 1) * 64;

  const int flat = blockIdx.x;
  const int xcd = flat & 7, idx = flat >> 3;   // idx in [0,128)
  const int bm = (xcd * 16 + (idx >> 3)) * 64; // bm tile in [0,128)
  const int bn = (idx & 7) * 128;              // bn tile in [0,8)

  const int r0 = tid >> 2;
  const int co = ((tid & 3) ^ ((tid >> 3) & 3)) * 8;
  const int xs = (quad ^ ((l16 >> 1) & 3)) * 8;

  floatx4 acc[2][4] = {};
  short8 afA[2], bfA[4], afB[2], bfB[4];

#define STAGE_P(kt, bf_)                                                     \
  do {                                                                       \
    const int k0_ = (kt) * 32;                                               \
    GLDS(&A[(size_t)(bm + r0) * 1024 + k0_ + co], &As[bf_][tid * 8]);        \
    GLDS(&Bt[(size_t)(bn + r0) * 1024 + k0_ + co], &Bs[bf_][tid * 8]);       \
    GLDS(&Bt[(size_t)(bn + r0 + 64) * 1024 + k0_ + co],                      \
         &Bs[bf_][(tid + 256) * 8]);                                         \
  } while (0)

  STAGE_P(0, 0);
  STAGE_P(1, 1);
  STAGE_P(2, 2);
  asm volatile("s_waitcnt vmcnt(6)" ::: "memory");
  __builtin_amdgcn_s_barrier();
  __builtin_amdgcn_sched_barrier(0);
#pragma unroll
  for (int i = 0; i < 2; i++)
    afA[i] = *(const short8*)&As[0][(wm + i * 16 + l16) * 32 + xs];
#pragma unroll
  for (int i = 0; i < 4; i++)
    bfA[i] = *(const short8*)&Bs[0][(wn + i * 16 + l16) * 32 + xs];
  asm volatile("s_waitcnt lgkmcnt(0)" ::: "memory");
  __builtin_amdgcn_sched_barrier(0);

#define KBODYP(kt, CA, CB, NA, NB)                                           \
  {                                                                          \
    if ((kt) <= 29)                                                          \
      asm volatile("s_waitcnt vmcnt(3)" ::: "memory");                       \
    else if ((kt) == 30)                                                     \
      asm volatile("s_waitcnt vmcnt(0)" ::: "memory");                       \
    __builtin_amdgcn_s_barrier();                                            \
    __builtin_amdgcn_sched_barrier(0);                                       \
    const int cs_ = (kt) % 3, ns_ = ((kt) + 1) % 3;                          \
    if ((kt) + 3 < 32) STAGE_P((kt) + 3, cs_);                               \
    if ((kt) + 1 < 32) {                                                     \
      _Pragma("unroll") for (int i = 0; i < 2; i++)                          \
          NA[i] = *(const short8*)&As[ns_][(wm + i * 16 + l16) * 32 + xs];   \
      _Pragma("unroll") for (int i = 0; i < 4; i++)                          \
          NB[i] = *(const short8*)&Bs[ns_][(wn + i * 16 + l16) * 32 + xs];   \
    }                                                                        \
    __builtin_amdgcn_s_setprio(1);                                           \
    _Pragma("unroll") for (int mi = 0; mi < 2; mi++)                         \
        _Pragma("unroll") for (int ni = 0; ni < 4; ni++)                     \
            acc[mi][ni] = __builtin_amdgcn_mfma_f32_16x16x32_bf16(           \
                CA[mi], CB[ni], acc[mi][ni], 0, 0, 0);                       \
    __builtin_amdgcn_s_setprio(0);                                           \
    asm volatile("s_waitcnt lgkmcnt(0)" ::: "memory");                       \
    __builtin_amdgcn_sched_barrier(0);                                       \
  }

  for (int kt = 0; kt < 32; kt += 2) {
    KBODYP(kt, afA, bfA, afB, bfB);
    KBODYP(kt + 1, afB, bfB, afA, bfA);
  }
#undef KBODYP
#undef STAGE_P

  const bool inbf = (*flag != 0);

#pragma unroll
  for (int mi = 0; mi < 2; mi++) {
#pragma unroll
    for (int ni = 0; ni < 4; ni++) {
#pragma unroll
      for (int r = 0; r < 4; r++) {
        int row = bm + wm + mi * 16 + quad * 4 + r;
        int col = bn + wn + ni * 16 + l16;
        float bsv = inbf ? bf2f(((const ushort_t*)bias)[col])
                         : ((const float*)bias)[col];
        float v = acc[mi][ni][r] + bsv;
        size_t idx2 = (size_t)row * CCH + col;
        if (inbf)
          ((ushort_t*)outp)[idx2] = f2bf(v);
        else
          ((float*)outp)[idx2] = v;
      }
    }
  }
}

// ---------------------------------------------------------------------------
// Flash attention v6: occupancy-split (stable since round 1; ~62 us).
//   One block per (bh, qt) -> 1024 blocks; each of the 4 waves owns one
//   32-row strip. Depth-1 prefetch, single barrier per tile. Softmax
//   denominator via MFMA row-sum. Long blocks dispatch first.
// Q,K: [B,H,T,64]. Vt: [B,H,64,T]. Out attb: [B,T,H*64] bf16.
// ---------------------------------------------------------------------------
__global__ __launch_bounds__(256, 3) void flash_attn(
    const ushort_t* __restrict__ qb, const ushort_t* __restrict__ kb,
    const ushort_t* __restrict__ vtb, ushort_t* __restrict__ attb) {
  alignas(16) __shared__ ushort_t Ks[2][64 * 64];
  alignas(16) __shared__ ushort_t Vs[2][64 * 64];
  alignas(16) __shared__ ushort_t Ps[4][32 * 72];

  const int tid = threadIdx.x;
  const int wave = tid >> 6, lane = tid & 63;
  const int quad = lane >> 4, l16 = lane & 15;
  const int bh = blockIdx.x;          // XCD-swizzle: bh fastest-varying
  const int b = bh >> 4, h = bh & 15;
  const int qt = 15 - blockIdx.y;     // long blocks dispatch first
  const int qbs = qt * 128 + wave * 32;

  const ushort_t* Q = qb + (size_t)bh * TT * HDIM;
  const ushort_t* K = kb + (size_t)bh * TT * HDIM;
  const ushort_t* Vt = vtb + (size_t)bh * HDIM * TT;
  ushort_t* Pw = Ps[wave];

  const float SC = 0.015625f * 1.44269504089f; // (1/64)*log2(e)

  // Q fragments, pre-scaled by SC
  short8 qf[2][2];
#pragma unroll
  for (int m = 0; m < 2; m++)
#pragma unroll
    for (int ks = 0; ks < 2; ks++) {
      short8 a = *(const short8*)&Q[(size_t)(qbs + m * 16 + l16) * HDIM +
                                    ks * 32 + quad * 8];
#pragma unroll
      for (int j = 0; j < 8; j++)
        a[j] = (short)f2bf(bf2f((ushort_t)a[j]) * SC);
      qf[m][ks] = a;
    }

  // A-fragment of all-ones (bf16 1.0) for the row-sum MFMA
  short8 ones;
#pragma unroll
  for (int j = 0; j < 8; j++) ones[j] = (short)0x3F80;

  floatx4 o[2][4] = {};
  floatx4 osum[2] = {};

  const int lt = (qbs + 31) >> 6;  // this wave's last live tile
  const int ntiles = 2 * qt + 2;   // block-uniform trip count
  int cur = 0;

  // prologue: stage tile 0 into buffer 0 (first barrier drains vmcnt)
#pragma unroll
  for (int s2 = 0; s2 < 2; s2++) {
    int c = tid + s2 * 256;
    int row = c >> 3, gc = ((c & 7) ^ (row & 7)) * 8;
    GLDS(&K[(size_t)row * HDIM + gc], &Ks[0][c * 8]);
    GLDS(&Vt[(size_t)row * TT + gc], &Vs[0][c * 8]);
  }

  for (int kt = 0; kt < ntiles; kt++) {
    const int kt0 = kt * 64;
    cur = kt & 1;
    // Single barrier per tile: implicit vmcnt(0) drain completes tile kt's
    // GLDS (issued last iteration under compute), and proves all waves are
    // done reading buf[cur^1] before it is restaged.
    __syncthreads();

    if (kt + 1 < ntiles) {
      const int n0 = kt0 + 64;
#pragma unroll
      for (int s2 = 0; s2 < 2; s2++) {
        int c = tid + s2 * 256;
        int row = c >> 3, gc = ((c & 7) ^ (row & 7)) * 8;
        GLDS(&K[(size_t)(n0 + row) * HDIM + gc], &Ks[cur ^ 1][c * 8]);
        GLDS(&Vt[(size_t)row * TT + n0 + gc], &Vs[cur ^ 1][c * 8]);
      }
    }

    if (kt > lt) continue;  // wave-uniform: this strip is done (barrier-safe)

    short8 kf[4][2];
#pragma unroll
    for (int sub = 0; sub < 4; sub++)
#pragma unroll
      for (int ks = 0; ks < 2; ks++) {
        int col = (ks * 32 + quad * 8) ^ ((l16 & 7) * 8);
        kf[sub][ks] = *(const short8*)&Ks[cur][(sub * 16 + l16) * 64 + col];
      }

#pragma unroll
    for (int m = 0; m < 2; m++) {
      floatx4 s[4] = {};
      __builtin_amdgcn_s_setprio(1);
#pragma unroll
      for (int sub = 0; sub < 4; sub++)
#pragma unroll
        for (int ks = 0; ks < 2; ks++)
          s[sub] = __builtin_amdgcn_mfma_f32_16x16x32_bf16(
              kf[sub][ks], qf[m][ks], s[sub], 0, 0, 0); // S^T tile
      __builtin_amdgcn_s_setprio(0);

      const bool full = (kt0 + 63 <= qbs + m * 16); // wave-uniform
      const int qrow = qbs + m * 16 + l16;
#pragma unroll
      for (int sub = 0; sub < 4; sub++) {
#pragma unroll
        for (int r = 0; r < 4; r++) {
          float p = EXP2(s[sub][r]);
          if (!full) {
            int key = kt0 + sub * 16 + quad * 4 + r;
            p = (key <= qrow) ? p : 0.0f;
          }
          s[sub][r] = p;
        }
        // P[q=l16][key-local sub*16+quad*4+{0..3}]: 4 contiguous bf16
        uint2v u;
        u[0] = pk_trunc(s[sub][0], s[sub][1]);
        u[1] = pk_trunc(s[sub][2], s[sub][3]);
        *(uint2v*)&Pw[(m * 16 + l16) * 72 + sub * 16 + quad * 4] = u;
      }
    }

    short8 pf[2][2];
#pragma unroll
    for (int m = 0; m < 2; m++)
#pragma unroll
      for (int ks = 0; ks < 2; ks++)
        pf[m][ks] =
            *(const short8*)&Pw[(m * 16 + l16) * 72 + ks * 32 + quad * 8];

    __builtin_amdgcn_s_setprio(1);
#pragma unroll
    for (int m = 0; m < 2; m++)
#pragma unroll
      for (int ks = 0; ks < 2; ks++)
        osum[m] = __builtin_amdgcn_mfma_f32_16x16x32_bf16(
            ones, pf[m][ks], osum[m], 0, 0, 0); // row-sum: C[r][q]=sum_k P

#pragma unroll
    for (int n = 0; n < 4; n++) {
#pragma unroll
      for (int ks = 0; ks < 2; ks++) {
        int col = (ks * 32 + quad * 8) ^ ((l16 & 7) * 8);
        short8 vf = *(const short8*)&Vs[cur][(n * 16 + l16) * 64 + col];
#pragma unroll
        for (int m = 0; m < 2; m++)
          o[m][n] = __builtin_amdgcn_mfma_f32_16x16x32_bf16(
              vf, pf[m][ks], o[m][n], 0, 0, 0); // O^T tile
      }
    }
    __builtin_amdgcn_s_setprio(0);
  }

  // epilogue: osum[m] already holds the complete row-sum for q=l16
#pragma unroll
  for (int m = 0; m < 2; m++) {
    float inv = 1.0f / osum[m][0];
    ushort_t* base =
        &attb[((size_t)(b * TT + qbs + m * 16 + l16)) * CCH + h * HDIM];
#pragma unroll
    for (int n = 0; n < 4; n++) {
      uint2v u;
      u[0] = pk_rne(o[m][n][0] * inv, o[m][n][1] * inv);
      u[1] = pk_rne(o[m][n][2] * inv, o[m][n][3] * inv);
      *(uint2v*)&base[n * 16 + quad * 4] = u;
    }
  }
}

// ---------------------------------------------------------------------------
// Workspace (bf16 elements), ~59 MB:
//   xb/attb [8192,1024] @ 0          (8,388,608)  attb overlays xb (dead)
//   wqkvT  [3072,1024]  @ 8,388,608  (3,145,728)
//   wprojT [1024,1024]  @ 11,534,336 (1,048,576)
//   qb     [B,H,T,64]   @ 12,582,912 (8,388,608)
//   kb     [B,H,T,64]   @ 20,971,520 (8,388,608)
//   flag   (uint)       @ 29,360,128
// vtb [B,H,64,T] lives in d_out (dead before proj GEMM writes it).
// Launch graph: prep_all -> gemm_qkv -> flash_attn -> gemm_proj (4 kernels).
// ---------------------------------------------------------------------------
extern "C" void kernel_launch(void* const* d_in, const int* in_sizes, int n_in,
                              void* d_out, int out_size, void* d_ws, size_t ws_size,
                              hipStream_t stream) {
  const void* x      = d_in[0];
  const void* w_qkv  = d_in[1];
  const void* b_qkv  = d_in[2];
  const void* w_proj = d_in[3];
  const void* b_proj = d_in[4];

  ushort_t* ws = (ushort_t*)d_ws;
  ushort_t* xb     = ws;
  ushort_t* wqkvT  = ws + 8388608;
  ushort_t* wprojT = ws + 11534336;
  ushort_t* qb     = ws + 12582912;
  ushort_t* kb     = ws + 20971520;
  ushort_t* attb   = xb;
  uint_t*   flag   = (uint_t*)(ws + 29360128);
  ushort_t* vtb    = (ushort_t*)d_out;

  prep_all<<<dim3(4096 + 768 + 256), dim3(256), 0, stream>>>(
      x, w_qkv, w_proj, xb, wqkvT, wprojT, flag);

  // 1D grid, 2-D rect XCD partition (1536 = 8 x 192)
  gemm_qkv<<<dim3((MROWS / 128) * ((3 * CCH) / 128)), dim3(256), 0, stream>>>(
      xb, wqkvT, b_qkv, qb, kb, vtb, flag);

  // grid (bh, qt): bh%8 -> XCD (L2 K/V reuse); y=0 (qt=15, longest) first
  flash_attn<<<dim3(BB * HH, 16), dim3(256), 0, stream>>>(qb, kb, vtb, attb);

  // 1D grid, 2-D rect XCD partition (1024 = 8 x 128); 64x128 tile
  gemm_proj<<<dim3((MROWS / 64) * (CCH / 128)), dim3(256), 0, stream>>>(
      attb, wprojT, b_proj, d_out, flag);
}